// Round 5
// baseline (271.877 us; speedup 1.0000x reference)
//
#include <hip/hip_runtime.h>

typedef _Float16 half8 __attribute__((ext_vector_type(8)));
typedef _Float16 half4 __attribute__((ext_vector_type(4)));
typedef float f32x4 __attribute__((ext_vector_type(4)));

// B=8, L1=L2=1024, D_IN=768, H=12, DK=DV=64, M=B*L=8192

// ---------------------------------------------------------------------------
// Projection GEMM: C[M=8192][768] = A[M][768] @ W[768][768] + bias -> fp16
// TRANS=0: out[m*768 + n]                  (K layout [B*L2][H*DK])
// TRANS=1: out[(b*768 + n)*1024 + (m&1023)] (Vt layout [B][H*DV][L2])
// ---------------------------------------------------------------------------
template<int TRANS>
__global__ __launch_bounds__(256)
void proj_kernel(const float* __restrict__ A, const float* __restrict__ W,
                 const float* __restrict__ bias, _Float16* __restrict__ out)
{
    __shared__ __align__(16) char smem[34816];
    _Float16* const Alds = (_Float16*)smem;            // [128][40] padded
    _Float16* const Wlds = (_Float16*)smem + 128 * 40; // [128][40] (W^T tile)
    _Float16* const Tlds = (_Float16*)smem;            // [128][136] epilogue

    const int tid  = threadIdx.x;
    const int lane = tid & 63;
    const int wave = tid >> 6;
    const int lr = lane & 15, lg = lane >> 4;
    const int wm = wave >> 1, wn = wave & 1;
    const int m0 = blockIdx.x * 128;
    const int n0 = blockIdx.y * 128;

    f32x4 acc[4][4] = {};

    const int ar  = tid >> 3;        // 0..31 A tile row
    const int ac  = (tid & 7) * 4;   // A tile col (of 32)
    const int wkr = tid >> 5;        // 0..7  W tile k-row
    const int wc  = (tid & 31) * 4;  // 0..124 W tile col (of 128)

    for (int kb = 0; kb < 24; ++kb) {
        #pragma unroll
        for (int i = 0; i < 4; ++i) {
            const int row = ar + 32 * i;
            const float4 v = *(const float4*)(A + (m0 + row) * 768 + kb * 32 + ac);
            half4 hh = { (_Float16)v.x, (_Float16)v.y, (_Float16)v.z, (_Float16)v.w };
            *(half4*)(Alds + row * 40 + ac) = hh;
        }
        #pragma unroll
        for (int i = 0; i < 4; ++i) {
            const int k = wkr + 8 * i;
            const float4 v = *(const float4*)(W + (kb * 32 + k) * 768 + n0 + wc);
            Wlds[(wc + 0) * 40 + k] = (_Float16)v.x;
            Wlds[(wc + 1) * 40 + k] = (_Float16)v.y;
            Wlds[(wc + 2) * 40 + k] = (_Float16)v.z;
            Wlds[(wc + 3) * 40 + k] = (_Float16)v.w;
        }
        __syncthreads();

        half8 af[4], bf[4];
        #pragma unroll
        for (int mt = 0; mt < 4; ++mt)
            af[mt] = *(const half8*)(Alds + (wm * 64 + mt * 16 + lr) * 40 + lg * 8);
        #pragma unroll
        for (int nt = 0; nt < 4; ++nt)
            bf[nt] = *(const half8*)(Wlds + (wn * 64 + nt * 16 + lr) * 40 + lg * 8);
        #pragma unroll
        for (int mt = 0; mt < 4; ++mt)
            #pragma unroll
            for (int nt = 0; nt < 4; ++nt)
                acc[mt][nt] = __builtin_amdgcn_mfma_f32_16x16x32_f16(af[mt], bf[nt], acc[mt][nt], 0, 0, 0);
        __syncthreads();
    }

    #pragma unroll
    for (int nt = 0; nt < 4; ++nt) {
        const int col = wn * 64 + nt * 16 + lr;
        const float bs = bias[n0 + col];
        #pragma unroll
        for (int mt = 0; mt < 4; ++mt) {
            #pragma unroll
            for (int r = 0; r < 4; ++r) {
                const int row = wm * 64 + mt * 16 + lg * 4 + r;
                const float val = acc[mt][nt][r] + bs;
                if (TRANS) Tlds[col * 136 + row] = (_Float16)val;
                else       Tlds[row * 136 + col] = (_Float16)val;
            }
        }
    }
    __syncthreads();

    // coalesced copy-out: 256 threads x 8 x 16B = 128x128 fp16 (full tile)
    const int crow = tid >> 1;
    const int cb   = (tid & 1) * 64;
    const _Float16* lsrc = Tlds + crow * 136 + cb;
    _Float16* gdst;
    if (TRANS) {
        const int bb  = m0 >> 10;
        const int l2b = m0 & 1023;
        gdst = out + (bb * 768 + n0 + crow) * 1024 + l2b + cb;
    } else {
        gdst = out + (m0 + crow) * 768 + n0 + cb;
    }
    #pragma unroll
    for (int it = 0; it < 8; ++it)
        *(uint4*)(gdst + it * 8) = *(const uint4*)(lsrc + it * 8);
}

// ---------------------------------------------------------------------------
// Fused attention: per block (q-tile=64, h, b).
// Phase 1: Q-tile projection x[64x768] @ Wq[:, h*64..] -> Qlds (fp16).
// Phase 2: flash loop over kv tiles of 32 (K from ws, Vt from ws).
// ---------------------------------------------------------------------------
__global__ __launch_bounds__(256)
void attn_kernel(const float* __restrict__ x, const float* __restrict__ Wq,
                 const float* __restrict__ bq,
                 const _Float16* __restrict__ K, const _Float16* __restrict__ Vt,
                 const unsigned char* __restrict__ mask,
                 float* __restrict__ out)
{
    __shared__ __align__(16) char smem[19456];
    _Float16* const Qlds = (_Float16*)smem;   // [64][72]
    _Float16* const Xlds = Qlds + 64 * 72;    // ph1: x [64][40] | ph2: K [32][72]
    _Float16* const Vlds = Xlds + 64 * 40;    // ph1: WqT [64][40] | ph2: Vt [64][40]

    const int tid  = threadIdx.x;
    const int lane = tid & 63;
    const int wave = tid >> 6;
    const int lr = lane & 15, lg = lane >> 4;
    const int q0 = blockIdx.x * 64;
    const int h  = blockIdx.y;
    const int b  = blockIdx.z;

    // ---- phase 1: Q tile projection ----
    {
        const int xr = tid >> 2, xc = (tid & 3) * 8;   // x stage: 64 rows x 32 cols
        const int wk = tid >> 3, wn8 = (tid & 7) * 8;  // W stage: 32 k x 64 n
        f32x4 qacc[4] = {};
        for (int kb = 0; kb < 24; ++kb) {
            const float* xrow = x + (b * 1024 + q0 + xr) * 768 + kb * 32 + xc;
            const float4 v0 = *(const float4*)(xrow);
            const float4 v1 = *(const float4*)(xrow + 4);
            half4 h0 = { (_Float16)v0.x, (_Float16)v0.y, (_Float16)v0.z, (_Float16)v0.w };
            half4 h1 = { (_Float16)v1.x, (_Float16)v1.y, (_Float16)v1.z, (_Float16)v1.w };
            *(half4*)(Xlds + xr * 40 + xc)     = h0;
            *(half4*)(Xlds + xr * 40 + xc + 4) = h1;
            const float* wrow = Wq + (kb * 32 + wk) * 768 + h * 64 + wn8;
            const float4 w0 = *(const float4*)(wrow);
            const float4 w1 = *(const float4*)(wrow + 4);
            Vlds[(wn8 + 0) * 40 + wk] = (_Float16)w0.x;
            Vlds[(wn8 + 1) * 40 + wk] = (_Float16)w0.y;
            Vlds[(wn8 + 2) * 40 + wk] = (_Float16)w0.z;
            Vlds[(wn8 + 3) * 40 + wk] = (_Float16)w0.w;
            Vlds[(wn8 + 4) * 40 + wk] = (_Float16)w1.x;
            Vlds[(wn8 + 5) * 40 + wk] = (_Float16)w1.y;
            Vlds[(wn8 + 6) * 40 + wk] = (_Float16)w1.z;
            Vlds[(wn8 + 7) * 40 + wk] = (_Float16)w1.w;
            __syncthreads();

            const half8 af = *(const half8*)(Xlds + (wave * 16 + lr) * 40 + lg * 8);
            #pragma unroll
            for (int nt = 0; nt < 4; ++nt) {
                const half8 bf = *(const half8*)(Vlds + (nt * 16 + lr) * 40 + lg * 8);
                qacc[nt] = __builtin_amdgcn_mfma_f32_16x16x32_f16(af, bf, qacc[nt], 0, 0, 0);
            }
            __syncthreads();
        }
        #pragma unroll
        for (int nt = 0; nt < 4; ++nt) {
            const int d = nt * 16 + lr;
            const float bs = bq[h * 64 + d];
            #pragma unroll
            for (int r = 0; r < 4; ++r)
                Qlds[(wave * 16 + lg * 4 + r) * 72 + d] = (_Float16)(qacc[nt][r] + bs);
        }
        __syncthreads();
    }

    // Q fragment (B-operand of S^T): lane holds Q[q=lr][d = 32*s + 8*lg + j]
    half8 qf[2];
    qf[0] = *(const half8*)(Qlds + (wave * 16 + lr) * 72 + lg * 8);
    qf[1] = *(const half8*)(Qlds + (wave * 16 + lr) * 72 + 32 + lg * 8);

    f32x4 o[4] = {};
    float m_run = -1e30f, l_run = 0.f;

    const int skv = tid >> 3, sdc = (tid & 7) * 8;  // K staging
    const int svd = tid >> 2, svk = (tid & 3) * 8;  // Vt staging
    const _Float16* const Kg = K + (b * 1024) * 768 + h * 64;
    const _Float16* const Vg = Vt + (b * 768 + h * 64) * 1024;
    const unsigned char* const mg = mask + b * 1024;

    for (int kt = 0; kt < 32; ++kt) {
        const int kv0 = kt * 32;
        *(uint4*)(Xlds + skv * 72 + sdc) = *(const uint4*)(Kg + (kv0 + skv) * 768 + sdc);
        *(uint4*)(Vlds + svd * 40 + svk) = *(const uint4*)(Vg + svd * 1024 + kv0 + svk);
        __syncthreads();

        // S^T tiles: rows kv (2 sub-tiles of 16), cols q (16)
        f32x4 st[2] = {};
        #pragma unroll
        for (int t2 = 0; t2 < 2; ++t2)
            #pragma unroll
            for (int s = 0; s < 2; ++s) {
                const half8 a = *(const half8*)(Xlds + (t2 * 16 + lr) * 72 + s * 32 + lg * 8);
                st[t2] = __builtin_amdgcn_mfma_f32_16x16x32_f16(a, qf[s], st[t2], 0, 0, 0);
            }

        float sv[2][4];
        #pragma unroll
        for (int t2 = 0; t2 < 2; ++t2) {
            const uchar4 mk = *(const uchar4*)(mg + kv0 + t2 * 16 + lg * 4);
            sv[t2][0] = mk.x ? -1e30f : st[t2][0] * 0.125f;
            sv[t2][1] = mk.y ? -1e30f : st[t2][1] * 0.125f;
            sv[t2][2] = mk.z ? -1e30f : st[t2][2] * 0.125f;
            sv[t2][3] = mk.w ? -1e30f : st[t2][3] * 0.125f;
        }

        // online softmax for q = lr (partners: lanes lr+16g)
        float mx = sv[0][0];
        #pragma unroll
        for (int t2 = 0; t2 < 2; ++t2)
            #pragma unroll
            for (int r = 0; r < 4; ++r) mx = fmaxf(mx, sv[t2][r]);
        mx = fmaxf(mx, __shfl_xor(mx, 16));
        mx = fmaxf(mx, __shfl_xor(mx, 32));
        const float m_new = fmaxf(m_run, mx);
        const float corr = __expf(m_run - m_new);

        float p[2][4];
        float ps = 0.f;
        #pragma unroll
        for (int t2 = 0; t2 < 2; ++t2)
            #pragma unroll
            for (int r = 0; r < 4; ++r) { p[t2][r] = __expf(sv[t2][r] - m_new); ps += p[t2][r]; }
        ps += __shfl_xor(ps, 16);
        ps += __shfl_xor(ps, 32);
        l_run = l_run * corr + ps;
        m_run = m_new;
        #pragma unroll
        for (int i = 0; i < 4; ++i) o[i] *= corr;

        // pack P to fp16 pairs
        unsigned int pb[2][2];
        #pragma unroll
        for (int t2 = 0; t2 < 2; ++t2)
            #pragma unroll
            for (int c = 0; c < 2; ++c) {
                union { _Float16 hx[2]; unsigned int u; } pk;
                pk.hx[0] = (_Float16)p[t2][2 * c];
                pk.hx[1] = (_Float16)p[t2][2 * c + 1];
                pb[t2][c] = pk.u;
            }

        // shuffle into PV B-fragment: lane(group g) needs kv = 8g..8g+7
        const int src0 = lr + ((lg & 1) ? 32 : 0);
        const int src1 = src0 + 16;
        const unsigned int w0a = __shfl(pb[0][0], src0), w1a = __shfl(pb[0][1], src0);
        const unsigned int w2a = __shfl(pb[0][0], src1), w3a = __shfl(pb[0][1], src1);
        const unsigned int w0b = __shfl(pb[1][0], src0), w1b = __shfl(pb[1][1], src0);
        const unsigned int w2b = __shfl(pb[1][0], src1), w3b = __shfl(pb[1][1], src1);
        const bool hi = (lg >= 2);
        union { unsigned int u[4]; half8 v; } pf;
        pf.u[0] = hi ? w0b : w0a;
        pf.u[1] = hi ? w1b : w1a;
        pf.u[2] = hi ? w2b : w2a;
        pf.u[3] = hi ? w3b : w3a;

        // O^T += V^T @ P^T
        #pragma unroll
        for (int dt = 0; dt < 4; ++dt) {
            const half8 a = *(const half8*)(Vlds + (dt * 16 + lr) * 40 + lg * 8);
            o[dt] = __builtin_amdgcn_mfma_f32_16x16x32_f16(a, pf.v, o[dt], 0, 0, 0);
        }
        __syncthreads();
    }

    const float inv = 1.f / l_run;
    const int qrow = b * 1024 + q0 + wave * 16 + lr;
    float* od = out + qrow * 768 + h * 64 + lg * 4;
    #pragma unroll
    for (int dt = 0; dt < 4; ++dt) {
        float4 v;
        v.x = o[dt][0] * inv; v.y = o[dt][1] * inv;
        v.z = o[dt][2] * inv; v.w = o[dt][3] * inv;
        *(float4*)(od + dt * 16) = v;
    }
}

extern "C" void kernel_launch(void* const* d_in, const int* in_sizes, int n_in,
                              void* d_out, int out_size, void* d_ws, size_t ws_size,
                              hipStream_t stream)
{
    const float* x  = (const float*)d_in[0];
    const float* y  = (const float*)d_in[1];
    const unsigned char* ym = (const unsigned char*)d_in[2];
    const float* Wq = (const float*)d_in[3];
    const float* bq = (const float*)d_in[4];
    const float* Wk = (const float*)d_in[5];
    const float* bk = (const float*)d_in[6];
    const float* Wv = (const float*)d_in[7];
    const float* bv = (const float*)d_in[8];

    _Float16* kws = (_Float16*)d_ws;             // [8192][768] fp16
    _Float16* vws = kws + 8192 * 768;            // [B][H*DV][L2] fp16 (V^T)

    dim3 pg(64, 6);
    proj_kernel<0><<<pg, 256, 0, stream>>>(y, Wk, bk, kws);
    proj_kernel<1><<<pg, 256, 0, stream>>>(y, Wv, bv, vws);

    dim3 ag(16, 12, 8);
    attn_kernel<<<ag, 256, 0, stream>>>(x, Wq, bq, kws, vws, ym, (float*)d_out);
}

// Round 6
// 166.721 us; speedup vs baseline: 1.6307x; 1.6307x over previous
//
#include <hip/hip_runtime.h>

typedef _Float16 half8 __attribute__((ext_vector_type(8)));
typedef _Float16 half4 __attribute__((ext_vector_type(4)));
typedef float f32x4 __attribute__((ext_vector_type(4)));

// B=8, L1=L2=1024, D_IN=768, H=12, DK=DV=64, M=B*L=8192

// ---------------------------------------------------------------------------
// One-time W transpose+convert: Wt[z][n][k] fp16 = W_z[k][n] fp32, z in {q,k,v}
// ---------------------------------------------------------------------------
__global__ __launch_bounds__(256)
void wtrans_kernel(const float* __restrict__ Wq, const float* __restrict__ Wk,
                   const float* __restrict__ Wv, _Float16* __restrict__ Wt)
{
    __shared__ float t[32][33];
    const float* W = (blockIdx.z == 0) ? Wq : (blockIdx.z == 1) ? Wk : Wv;
    _Float16* dst = Wt + blockIdx.z * 768 * 768;
    const int tx = threadIdx.x & 31, ty = threadIdx.x >> 5;
    const int k0 = blockIdx.y * 32, n0 = blockIdx.x * 32;
    #pragma unroll
    for (int i = 0; i < 4; ++i)
        t[ty + 8 * i][tx] = W[(k0 + ty + 8 * i) * 768 + n0 + tx];
    __syncthreads();
    #pragma unroll
    for (int i = 0; i < 4; ++i)
        dst[(n0 + ty + 8 * i) * 768 + k0 + tx] = (_Float16)t[tx][ty + 8 * i];
}

// ---------------------------------------------------------------------------
// Merged K/V projection GEMM: C[8192][768] = y @ W + bias -> fp16
// z=0: K, out[m*768+n].  z=1: V, out[(b*768+n)*1024 + (m&1023)] (Vt).
// W comes pre-transposed fp16: Wt[n][k].
// ---------------------------------------------------------------------------
__global__ __launch_bounds__(256)
void proj_kernel(const float* __restrict__ A, const _Float16* __restrict__ Wt,
                 const float* __restrict__ bk, const float* __restrict__ bv,
                 _Float16* __restrict__ kout, _Float16* __restrict__ vout)
{
    __shared__ __align__(16) char smem[34816];
    _Float16* const Alds = (_Float16*)smem;            // [128][40] padded
    _Float16* const Wlds = (_Float16*)smem + 128 * 40; // [128][40] (W^T tile)
    _Float16* const Tlds = (_Float16*)smem;            // [128][136] epilogue

    const int tid  = threadIdx.x;
    const int lane = tid & 63;
    const int wave = tid >> 6;
    const int lr = lane & 15, lg = lane >> 4;
    const int wm = wave >> 1, wn = wave & 1;
    const int m0 = blockIdx.x * 128;
    const int n0 = blockIdx.y * 128;
    const int isv = blockIdx.z;

    const _Float16* __restrict__ W = Wt + (1 + isv) * 768 * 768; // Wtk or Wtv
    const float* __restrict__ bias = isv ? bv : bk;

    f32x4 acc[4][4] = {};

    const int ar   = tid >> 3;        // 0..31 A tile row
    const int ac   = (tid & 7) * 4;   // A tile col (of 32)
    const int wrow = tid >> 1;        // 0..127 Wt tile n-row
    const int wcb  = (tid & 1) * 16;  // 0/16 halves within 32-k row

    for (int kb = 0; kb < 24; ++kb) {
        #pragma unroll
        for (int i = 0; i < 4; ++i) {
            const int row = ar + 32 * i;
            const float4 v = *(const float4*)(A + (m0 + row) * 768 + kb * 32 + ac);
            half4 hh = { (_Float16)v.x, (_Float16)v.y, (_Float16)v.z, (_Float16)v.w };
            *(half4*)(Alds + row * 40 + ac) = hh;
        }
        {
            const _Float16* wtr = W + (n0 + wrow) * 768 + kb * 32 + wcb;
            *(uint4*)(Wlds + wrow * 40 + wcb)     = *(const uint4*)(wtr);
            *(uint4*)(Wlds + wrow * 40 + wcb + 8) = *(const uint4*)(wtr + 8);
        }
        __syncthreads();

        half8 af[4], bf[4];
        #pragma unroll
        for (int mt = 0; mt < 4; ++mt)
            af[mt] = *(const half8*)(Alds + (wm * 64 + mt * 16 + lr) * 40 + lg * 8);
        #pragma unroll
        for (int nt = 0; nt < 4; ++nt)
            bf[nt] = *(const half8*)(Wlds + (wn * 64 + nt * 16 + lr) * 40 + lg * 8);
        #pragma unroll
        for (int mt = 0; mt < 4; ++mt)
            #pragma unroll
            for (int nt = 0; nt < 4; ++nt)
                acc[mt][nt] = __builtin_amdgcn_mfma_f32_16x16x32_f16(af[mt], bf[nt], acc[mt][nt], 0, 0, 0);
        __syncthreads();
    }

    #pragma unroll
    for (int nt = 0; nt < 4; ++nt) {
        const int col = wn * 64 + nt * 16 + lr;
        const float bs = bias[n0 + col];
        #pragma unroll
        for (int mt = 0; mt < 4; ++mt) {
            #pragma unroll
            for (int r = 0; r < 4; ++r) {
                const int row = wm * 64 + mt * 16 + lg * 4 + r;
                const float val = acc[mt][nt][r] + bs;
                if (isv) Tlds[col * 136 + row] = (_Float16)val;
                else     Tlds[row * 136 + col] = (_Float16)val;
            }
        }
    }
    __syncthreads();

    // coalesced copy-out: 256 threads x 8 x 16B = 128x128 fp16 (full tile)
    const int crow = tid >> 1;
    const int cb   = (tid & 1) * 64;
    const _Float16* lsrc = Tlds + crow * 136 + cb;
    _Float16* gdst;
    if (isv) {
        const int bb  = m0 >> 10;
        const int l2b = m0 & 1023;
        gdst = vout + (bb * 768 + n0 + crow) * 1024 + l2b + cb;
    } else {
        gdst = kout + (m0 + crow) * 768 + n0 + cb;
    }
    #pragma unroll
    for (int it = 0; it < 8; ++it)
        *(uint4*)(gdst + it * 8) = *(const uint4*)(lsrc + it * 8);
}

// ---------------------------------------------------------------------------
// Fused attention: per block (q-tile=64, h, b).
// Phase 1: Q-tile projection x[64x768] @ Wq^T-slice -> Qlds (fp16).
// Phase 2: flash loop over kv tiles of 32 (K from ws, Vt from ws).
// ---------------------------------------------------------------------------
__global__ __launch_bounds__(256)
void attn_kernel(const float* __restrict__ x, const _Float16* __restrict__ Wtq,
                 const float* __restrict__ bq,
                 const _Float16* __restrict__ K, const _Float16* __restrict__ Vt,
                 const unsigned char* __restrict__ mask,
                 float* __restrict__ out)
{
    __shared__ __align__(16) char smem[19456];
    _Float16* const Qlds = (_Float16*)smem;   // [64][72]
    _Float16* const Xlds = Qlds + 64 * 72;    // ph1: x [64][40] | ph2: K [32][72]
    _Float16* const Vlds = Xlds + 64 * 40;    // ph1: WqT [64][40] | ph2: Vt [64][40]

    const int tid  = threadIdx.x;
    const int lane = tid & 63;
    const int wave = tid >> 6;
    const int lr = lane & 15, lg = lane >> 4;
    const int q0 = blockIdx.x * 64;
    const int h  = blockIdx.y;
    const int b  = blockIdx.z;

    // ---- phase 1: Q tile projection (Wq^T rows staged as vectors) ----
    {
        const int xr = tid >> 2, xc = (tid & 3) * 8;   // x stage: 64 rows x 32 cols
        const int wr = tid >> 2, wc8 = (tid & 3) * 8;  // Wt stage: 64 n x 32 k
        f32x4 qacc[4] = {};
        for (int kb = 0; kb < 24; ++kb) {
            const float* xrow = x + (b * 1024 + q0 + xr) * 768 + kb * 32 + xc;
            const float4 v0 = *(const float4*)(xrow);
            const float4 v1 = *(const float4*)(xrow + 4);
            half4 h0 = { (_Float16)v0.x, (_Float16)v0.y, (_Float16)v0.z, (_Float16)v0.w };
            half4 h1 = { (_Float16)v1.x, (_Float16)v1.y, (_Float16)v1.z, (_Float16)v1.w };
            *(half4*)(Xlds + xr * 40 + xc)     = h0;
            *(half4*)(Xlds + xr * 40 + xc + 4) = h1;
            *(uint4*)(Vlds + wr * 40 + wc8) =
                *(const uint4*)(Wtq + (h * 64 + wr) * 768 + kb * 32 + wc8);
            __syncthreads();

            const half8 af = *(const half8*)(Xlds + (wave * 16 + lr) * 40 + lg * 8);
            #pragma unroll
            for (int nt = 0; nt < 4; ++nt) {
                const half8 bf = *(const half8*)(Vlds + (nt * 16 + lr) * 40 + lg * 8);
                qacc[nt] = __builtin_amdgcn_mfma_f32_16x16x32_f16(af, bf, qacc[nt], 0, 0, 0);
            }
            __syncthreads();
        }
        #pragma unroll
        for (int nt = 0; nt < 4; ++nt) {
            const int d = nt * 16 + lr;
            const float bs = bq[h * 64 + d];
            #pragma unroll
            for (int r = 0; r < 4; ++r)
                Qlds[(wave * 16 + lg * 4 + r) * 72 + d] = (_Float16)(qacc[nt][r] + bs);
        }
        __syncthreads();
    }

    // Q fragment (B-operand of S^T): lane holds Q[q=lr][d = 32*s + 8*lg + j]
    half8 qf[2];
    qf[0] = *(const half8*)(Qlds + (wave * 16 + lr) * 72 + lg * 8);
    qf[1] = *(const half8*)(Qlds + (wave * 16 + lr) * 72 + 32 + lg * 8);

    f32x4 o[4] = {};
    float m_run = -1e30f, l_run = 0.f;

    const int skv = tid >> 3, sdc = (tid & 7) * 8;  // K staging
    const int svd = tid >> 2, svk = (tid & 3) * 8;  // Vt staging
    const _Float16* const Kg = K + (b * 1024) * 768 + h * 64;
    const _Float16* const Vg = Vt + (b * 768 + h * 64) * 1024;
    const unsigned char* const mg = mask + b * 1024;

    for (int kt = 0; kt < 32; ++kt) {
        const int kv0 = kt * 32;
        *(uint4*)(Xlds + skv * 72 + sdc) = *(const uint4*)(Kg + (kv0 + skv) * 768 + sdc);
        *(uint4*)(Vlds + svd * 40 + svk) = *(const uint4*)(Vg + svd * 1024 + kv0 + svk);
        __syncthreads();

        // S^T tiles: rows kv (2 sub-tiles of 16), cols q (16)
        f32x4 st[2] = {};
        #pragma unroll
        for (int t2 = 0; t2 < 2; ++t2)
            #pragma unroll
            for (int s = 0; s < 2; ++s) {
                const half8 a = *(const half8*)(Xlds + (t2 * 16 + lr) * 72 + s * 32 + lg * 8);
                st[t2] = __builtin_amdgcn_mfma_f32_16x16x32_f16(a, qf[s], st[t2], 0, 0, 0);
            }

        float sv[2][4];
        #pragma unroll
        for (int t2 = 0; t2 < 2; ++t2) {
            const uchar4 mk = *(const uchar4*)(mg + kv0 + t2 * 16 + lg * 4);
            sv[t2][0] = mk.x ? -1e30f : st[t2][0] * 0.125f;
            sv[t2][1] = mk.y ? -1e30f : st[t2][1] * 0.125f;
            sv[t2][2] = mk.z ? -1e30f : st[t2][2] * 0.125f;
            sv[t2][3] = mk.w ? -1e30f : st[t2][3] * 0.125f;
        }

        // online softmax for q = lr (partners: lanes lr+16g)
        float mx = sv[0][0];
        #pragma unroll
        for (int t2 = 0; t2 < 2; ++t2)
            #pragma unroll
            for (int r = 0; r < 4; ++r) mx = fmaxf(mx, sv[t2][r]);
        mx = fmaxf(mx, __shfl_xor(mx, 16));
        mx = fmaxf(mx, __shfl_xor(mx, 32));
        const float m_new = fmaxf(m_run, mx);
        const float corr = __expf(m_run - m_new);

        float p[2][4];
        float ps = 0.f;
        #pragma unroll
        for (int t2 = 0; t2 < 2; ++t2)
            #pragma unroll
            for (int r = 0; r < 4; ++r) { p[t2][r] = __expf(sv[t2][r] - m_new); ps += p[t2][r]; }
        ps += __shfl_xor(ps, 16);
        ps += __shfl_xor(ps, 32);
        l_run = l_run * corr + ps;
        m_run = m_new;
        #pragma unroll
        for (int i = 0; i < 4; ++i) o[i] *= corr;

        // pack P to fp16 pairs
        unsigned int pb[2][2];
        #pragma unroll
        for (int t2 = 0; t2 < 2; ++t2)
            #pragma unroll
            for (int c = 0; c < 2; ++c) {
                union { _Float16 hx[2]; unsigned int u; } pk;
                pk.hx[0] = (_Float16)p[t2][2 * c];
                pk.hx[1] = (_Float16)p[t2][2 * c + 1];
                pb[t2][c] = pk.u;
            }

        // shuffle into PV B-fragment: lane(group g) needs kv = 8g..8g+7
        const int src0 = lr + ((lg & 1) ? 32 : 0);
        const int src1 = src0 + 16;
        const unsigned int w0a = __shfl(pb[0][0], src0), w1a = __shfl(pb[0][1], src0);
        const unsigned int w2a = __shfl(pb[0][0], src1), w3a = __shfl(pb[0][1], src1);
        const unsigned int w0b = __shfl(pb[1][0], src0), w1b = __shfl(pb[1][1], src0);
        const unsigned int w2b = __shfl(pb[1][0], src1), w3b = __shfl(pb[1][1], src1);
        const bool hi = (lg >= 2);
        union { unsigned int u[4]; half8 v; } pf;
        pf.u[0] = hi ? w0b : w0a;
        pf.u[1] = hi ? w1b : w1a;
        pf.u[2] = hi ? w2b : w2a;
        pf.u[3] = hi ? w3b : w3a;

        // O^T += V^T @ P^T
        #pragma unroll
        for (int dt = 0; dt < 4; ++dt) {
            const half8 a = *(const half8*)(Vlds + (dt * 16 + lr) * 40 + lg * 8);
            o[dt] = __builtin_amdgcn_mfma_f32_16x16x32_f16(a, pf.v, o[dt], 0, 0, 0);
        }
        __syncthreads();
    }

    const float inv = 1.f / l_run;
    const int qrow = b * 1024 + q0 + wave * 16 + lr;
    float* od = out + qrow * 768 + h * 64 + lg * 4;
    #pragma unroll
    for (int dt = 0; dt < 4; ++dt) {
        float4 v;
        v.x = o[dt][0] * inv; v.y = o[dt][1] * inv;
        v.z = o[dt][2] * inv; v.w = o[dt][3] * inv;
        *(float4*)(od + dt * 16) = v;
    }
}

extern "C" void kernel_launch(void* const* d_in, const int* in_sizes, int n_in,
                              void* d_out, int out_size, void* d_ws, size_t ws_size,
                              hipStream_t stream)
{
    const float* x  = (const float*)d_in[0];
    const float* y  = (const float*)d_in[1];
    const unsigned char* ym = (const unsigned char*)d_in[2];
    const float* Wq = (const float*)d_in[3];
    const float* bq = (const float*)d_in[4];
    const float* Wk = (const float*)d_in[5];
    const float* bk = (const float*)d_in[6];
    const float* Wv = (const float*)d_in[7];
    const float* bv = (const float*)d_in[8];

    _Float16* kws = (_Float16*)d_ws;             // [8192][768] fp16 K
    _Float16* vws = kws + 8192 * 768;            // [B][H*DV][L2] fp16 V^T
    _Float16* wt  = vws + 8192 * 768;            // [3][768][768] fp16 W^T (q,k,v)

    wtrans_kernel<<<dim3(24, 24, 3), 256, 0, stream>>>(Wq, Wk, Wv, wt);
    proj_kernel<<<dim3(64, 6, 2), 256, 0, stream>>>(y, wt, bk, bv, kws, vws);

    dim3 ag(16, 12, 8);
    attn_kernel<<<ag, 256, 0, stream>>>(x, wt, bq, kws, vws, ym, (float*)d_out);
}

// Round 7
// 134.300 us; speedup vs baseline: 2.0244x; 1.2414x over previous
//
#include <hip/hip_runtime.h>

typedef _Float16 half8 __attribute__((ext_vector_type(8)));
typedef _Float16 half4 __attribute__((ext_vector_type(4)));
typedef float f32x4 __attribute__((ext_vector_type(4)));

// B=8, L1=L2=1024, D_IN=768, H=12, DK=DV=64, M=B*L=8192

// ---------------------------------------------------------------------------
// One-time W transpose+convert: Wt[z][n][k] fp16 = W_z[k][n] fp32, z in {q,k,v}
// ---------------------------------------------------------------------------
__global__ __launch_bounds__(256)
void wtrans_kernel(const float* __restrict__ Wq, const float* __restrict__ Wk,
                   const float* __restrict__ Wv, _Float16* __restrict__ Wt)
{
    __shared__ float t[32][33];
    const float* W = (blockIdx.z == 0) ? Wq : (blockIdx.z == 1) ? Wk : Wv;
    _Float16* dst = Wt + blockIdx.z * 768 * 768;
    const int tx = threadIdx.x & 31, ty = threadIdx.x >> 5;
    const int k0 = blockIdx.y * 32, n0 = blockIdx.x * 32;
    #pragma unroll
    for (int i = 0; i < 4; ++i)
        t[ty + 8 * i][tx] = W[(k0 + ty + 8 * i) * 768 + n0 + tx];
    __syncthreads();
    #pragma unroll
    for (int i = 0; i < 4; ++i)
        dst[(n0 + ty + 8 * i) * 768 + k0 + tx] = (_Float16)t[tx][ty + 8 * i];
}

// ---------------------------------------------------------------------------
// Merged K/V projection GEMM: C[8192][768] = y @ W + bias -> fp16
// z=0: K, out[m*768+n].  z=1: V, out[(b*768+n)*1024 + (m&1023)] (Vt).
// ---------------------------------------------------------------------------
__global__ __launch_bounds__(256)
void proj_kernel(const float* __restrict__ A, const _Float16* __restrict__ Wt,
                 const float* __restrict__ bk, const float* __restrict__ bv,
                 _Float16* __restrict__ kout, _Float16* __restrict__ vout)
{
    __shared__ __align__(16) char smem[34816];
    _Float16* const Alds = (_Float16*)smem;            // [128][40] padded
    _Float16* const Wlds = (_Float16*)smem + 128 * 40; // [128][40] (W^T tile)
    _Float16* const Tlds = (_Float16*)smem;            // [128][136] epilogue

    const int tid  = threadIdx.x;
    const int lane = tid & 63;
    const int wave = tid >> 6;
    const int lr = lane & 15, lg = lane >> 4;
    const int wm = wave >> 1, wn = wave & 1;
    const int m0 = blockIdx.x * 128;
    const int n0 = blockIdx.y * 128;
    const int isv = blockIdx.z;

    const _Float16* __restrict__ W = Wt + (1 + isv) * 768 * 768;
    const float* __restrict__ bias = isv ? bv : bk;

    f32x4 acc[4][4] = {};

    const int ar   = tid >> 3;
    const int ac   = (tid & 7) * 4;
    const int wrow = tid >> 1;
    const int wcb  = (tid & 1) * 16;

    for (int kb = 0; kb < 24; ++kb) {
        #pragma unroll
        for (int i = 0; i < 4; ++i) {
            const int row = ar + 32 * i;
            const float4 v = *(const float4*)(A + (m0 + row) * 768 + kb * 32 + ac);
            half4 hh = { (_Float16)v.x, (_Float16)v.y, (_Float16)v.z, (_Float16)v.w };
            *(half4*)(Alds + row * 40 + ac) = hh;
        }
        {
            const _Float16* wtr = W + (n0 + wrow) * 768 + kb * 32 + wcb;
            *(uint4*)(Wlds + wrow * 40 + wcb)     = *(const uint4*)(wtr);
            *(uint4*)(Wlds + wrow * 40 + wcb + 8) = *(const uint4*)(wtr + 8);
        }
        __syncthreads();

        half8 af[4], bf[4];
        #pragma unroll
        for (int mt = 0; mt < 4; ++mt)
            af[mt] = *(const half8*)(Alds + (wm * 64 + mt * 16 + lr) * 40 + lg * 8);
        #pragma unroll
        for (int nt = 0; nt < 4; ++nt)
            bf[nt] = *(const half8*)(Wlds + (wn * 64 + nt * 16 + lr) * 40 + lg * 8);
        #pragma unroll
        for (int mt = 0; mt < 4; ++mt)
            #pragma unroll
            for (int nt = 0; nt < 4; ++nt)
                acc[mt][nt] = __builtin_amdgcn_mfma_f32_16x16x32_f16(af[mt], bf[nt], acc[mt][nt], 0, 0, 0);
        __syncthreads();
    }

    #pragma unroll
    for (int nt = 0; nt < 4; ++nt) {
        const int col = wn * 64 + nt * 16 + lr;
        const float bs = bias[n0 + col];
        #pragma unroll
        for (int mt = 0; mt < 4; ++mt) {
            #pragma unroll
            for (int r = 0; r < 4; ++r) {
                const int row = wm * 64 + mt * 16 + lg * 4 + r;
                const float val = acc[mt][nt][r] + bs;
                if (isv) Tlds[col * 136 + row] = (_Float16)val;
                else     Tlds[row * 136 + col] = (_Float16)val;
            }
        }
    }
    __syncthreads();

    const int crow = tid >> 1;
    const int cb   = (tid & 1) * 64;
    const _Float16* lsrc = Tlds + crow * 136 + cb;
    _Float16* gdst;
    if (isv) {
        const int bb  = m0 >> 10;
        const int l2b = m0 & 1023;
        gdst = vout + (bb * 768 + n0 + crow) * 1024 + l2b + cb;
    } else {
        gdst = kout + (m0 + crow) * 768 + n0 + cb;
    }
    #pragma unroll
    for (int it = 0; it < 8; ++it)
        *(uint4*)(gdst + it * 8) = *(const uint4*)(lsrc + it * 8);
}

// ---------------------------------------------------------------------------
// Fused attention: per block (q-tile=64, h, b).
// Phase 1: Q-tile projection, BK=64, async-staged.
// Phase 2: flash loop, KVBLK=64, async-staged, P via per-wave LDS roundtrip.
// ---------------------------------------------------------------------------
__global__ __launch_bounds__(256)
void attn_kernel(const float* __restrict__ x, const _Float16* __restrict__ Wtq,
                 const float* __restrict__ bq,
                 const _Float16* __restrict__ K, const _Float16* __restrict__ Vt,
                 const unsigned char* __restrict__ mask,
                 float* __restrict__ out)
{
    __shared__ __align__(16) char smem[37888];
    _Float16* const Qlds = (_Float16*)smem;                  // [64][72]
    _Float16* const Klds = (_Float16*)(smem + 9216);         // ph1: x   [64][72]
    _Float16* const Vlds = (_Float16*)(smem + 18432);        // ph1: WqT [64][72]
    _Float16* const Plds = (_Float16*)(smem + 27648);        // [4 waves][16][72]
    unsigned char* const Mlds = (unsigned char*)(smem + 36864); // [1024]

    const int tid  = threadIdx.x;
    const int lane = tid & 63;
    const int wave = tid >> 6;
    const int lr = lane & 15, lg = lane >> 4;
    const int q0 = blockIdx.x * 64;
    const int h  = blockIdx.y;
    const int b  = blockIdx.z;

    const int pr = tid >> 2;            // 0..63 staging row
    const int pc = (tid & 3) * 16;      // staging col (16 elems)

    // ---- phase 1: Q tile projection, BK=64, async-split ----
    {
        const float* xbase = x + (b * 1024 + q0 + pr) * 768 + pc;
        const _Float16* wbase = Wtq + (h * 64 + pr) * 768 + pc;
        float4 xa, xb, xc_, xd;
        uint4 wa, wb;
        xa = *(const float4*)(xbase);      xb = *(const float4*)(xbase + 4);
        xc_ = *(const float4*)(xbase + 8); xd = *(const float4*)(xbase + 12);
        wa = *(const uint4*)(wbase);       wb = *(const uint4*)(wbase + 8);

        f32x4 qacc[4] = {};
        for (int kb = 0; kb < 12; ++kb) {
            __syncthreads();
            half8 h0, h1;
            h0[0]=(_Float16)xa.x; h0[1]=(_Float16)xa.y; h0[2]=(_Float16)xa.z; h0[3]=(_Float16)xa.w;
            h0[4]=(_Float16)xb.x; h0[5]=(_Float16)xb.y; h0[6]=(_Float16)xb.z; h0[7]=(_Float16)xb.w;
            h1[0]=(_Float16)xc_.x; h1[1]=(_Float16)xc_.y; h1[2]=(_Float16)xc_.z; h1[3]=(_Float16)xc_.w;
            h1[4]=(_Float16)xd.x; h1[5]=(_Float16)xd.y; h1[6]=(_Float16)xd.z; h1[7]=(_Float16)xd.w;
            *(half8*)(Klds + pr * 72 + pc)     = h0;
            *(half8*)(Klds + pr * 72 + pc + 8) = h1;
            *(uint4*)(Vlds + pr * 72 + pc)     = wa;
            *(uint4*)(Vlds + pr * 72 + pc + 8) = wb;
            __syncthreads();
            if (kb < 11) {
                const float* xn = xbase + (kb + 1) * 64;
                const _Float16* wn = wbase + (kb + 1) * 64;
                xa = *(const float4*)(xn);      xb = *(const float4*)(xn + 4);
                xc_ = *(const float4*)(xn + 8); xd = *(const float4*)(xn + 12);
                wa = *(const uint4*)(wn);       wb = *(const uint4*)(wn + 8);
            }
            half8 af[2];
            af[0] = *(const half8*)(Klds + (wave * 16 + lr) * 72 + lg * 8);
            af[1] = *(const half8*)(Klds + (wave * 16 + lr) * 72 + 32 + lg * 8);
            #pragma unroll
            for (int nt = 0; nt < 4; ++nt) {
                #pragma unroll
                for (int s = 0; s < 2; ++s) {
                    const half8 bf = *(const half8*)(Vlds + (nt * 16 + lr) * 72 + s * 32 + lg * 8);
                    qacc[nt] = __builtin_amdgcn_mfma_f32_16x16x32_f16(af[s], bf, qacc[nt], 0, 0, 0);
                }
            }
        }
        #pragma unroll
        for (int nt = 0; nt < 4; ++nt) {
            const int d = nt * 16 + lr;
            const float bs = bq[h * 64 + d];
            #pragma unroll
            for (int r = 0; r < 4; ++r)
                Qlds[(wave * 16 + lg * 4 + r) * 72 + d] = (_Float16)(qacc[nt][r] + bs);
        }
        // stage mask slice once
        *(uchar4*)(Mlds + tid * 4) = *(const uchar4*)(mask + b * 1024 + tid * 4);
        __syncthreads();
    }

    // Q fragment (B-operand of S^T)
    half8 qf[2];
    qf[0] = *(const half8*)(Qlds + (wave * 16 + lr) * 72 + lg * 8);
    qf[1] = *(const half8*)(Qlds + (wave * 16 + lr) * 72 + 32 + lg * 8);

    f32x4 o[4] = {};
    float m_run = -1e30f, l_run = 0.f;

    const _Float16* const Kg = K + (b * 1024 + pr) * 768 + pc;
    const _Float16* const Vg = Vt + (b * 768 + h * 64 + pr) * 1024 + pc;
    _Float16* const Pw = Plds + wave * 1152;

    // prologue loads (kv tile 0)
    uint4 kr0, kr1, vr0, vr1;
    kr0 = *(const uint4*)(Kg + h * 64);
    kr1 = *(const uint4*)(Kg + h * 64 + 8);
    vr0 = *(const uint4*)(Vg);
    vr1 = *(const uint4*)(Vg + 8);

    for (int kt = 0; kt < 16; ++kt) {
        const int kv0 = kt * 64;
        __syncthreads();
        *(uint4*)(Klds + pr * 72 + pc)     = kr0;
        *(uint4*)(Klds + pr * 72 + pc + 8) = kr1;
        *(uint4*)(Vlds + pr * 72 + pc)     = vr0;
        *(uint4*)(Vlds + pr * 72 + pc + 8) = vr1;
        __syncthreads();
        if (kt < 15) {
            kr0 = *(const uint4*)(Kg + (kv0 + 64) * 768 + h * 64);
            kr1 = *(const uint4*)(Kg + (kv0 + 64) * 768 + h * 64 + 8);
            vr0 = *(const uint4*)(Vg + kv0 + 64);
            vr1 = *(const uint4*)(Vg + kv0 + 64 + 8);
        }

        // S^T: 4 kv-subtiles x 16 q
        f32x4 st[4] = {};
        #pragma unroll
        for (int t4 = 0; t4 < 4; ++t4)
            #pragma unroll
            for (int s = 0; s < 2; ++s) {
                const half8 a = *(const half8*)(Klds + (t4 * 16 + lr) * 72 + s * 32 + lg * 8);
                st[t4] = __builtin_amdgcn_mfma_f32_16x16x32_f16(a, qf[s], st[t4], 0, 0, 0);
            }

        // scale + mask
        float sv[4][4];
        #pragma unroll
        for (int t4 = 0; t4 < 4; ++t4) {
            const uchar4 mk = *(const uchar4*)(Mlds + kv0 + t4 * 16 + lg * 4);
            sv[t4][0] = mk.x ? -1e30f : st[t4][0] * 0.125f;
            sv[t4][1] = mk.y ? -1e30f : st[t4][1] * 0.125f;
            sv[t4][2] = mk.z ? -1e30f : st[t4][2] * 0.125f;
            sv[t4][3] = mk.w ? -1e30f : st[t4][3] * 0.125f;
        }

        // online softmax (q = lr; partners lr+16g)
        float mx = sv[0][0];
        #pragma unroll
        for (int t4 = 0; t4 < 4; ++t4)
            #pragma unroll
            for (int r = 0; r < 4; ++r) mx = fmaxf(mx, sv[t4][r]);
        mx = fmaxf(mx, __shfl_xor(mx, 16));
        mx = fmaxf(mx, __shfl_xor(mx, 32));
        const float m_new = fmaxf(m_run, mx);
        const float corr = __expf(m_run - m_new);

        float p[4][4];
        float ps = 0.f;
        #pragma unroll
        for (int t4 = 0; t4 < 4; ++t4)
            #pragma unroll
            for (int r = 0; r < 4; ++r) { p[t4][r] = __expf(sv[t4][r] - m_new); ps += p[t4][r]; }
        ps += __shfl_xor(ps, 16);
        ps += __shfl_xor(ps, 32);
        l_run = l_run * corr + ps;
        m_run = m_new;
        #pragma unroll
        for (int i = 0; i < 4; ++i) o[i] *= corr;

        // P -> per-wave LDS (4 x ds_write_b64), then read PV B-fragments
        #pragma unroll
        for (int t4 = 0; t4 < 4; ++t4) {
            half4 ph = { (_Float16)p[t4][0], (_Float16)p[t4][1],
                         (_Float16)p[t4][2], (_Float16)p[t4][3] };
            *(half4*)(Pw + lr * 72 + t4 * 16 + lg * 4) = ph;
        }
        asm volatile("s_waitcnt lgkmcnt(0)" ::: "memory");
        __builtin_amdgcn_sched_barrier(0);

        half8 pf[2];
        pf[0] = *(const half8*)(Pw + lr * 72 + lg * 8);
        pf[1] = *(const half8*)(Pw + lr * 72 + 32 + lg * 8);

        // O^T += V^T @ P^T
        #pragma unroll
        for (int dt = 0; dt < 4; ++dt)
            #pragma unroll
            for (int ks = 0; ks < 2; ++ks) {
                const half8 a = *(const half8*)(Vlds + (dt * 16 + lr) * 72 + ks * 32 + lg * 8);
                o[dt] = __builtin_amdgcn_mfma_f32_16x16x32_f16(a, pf[ks], o[dt], 0, 0, 0);
            }
    }

    const float inv = 1.f / l_run;
    const int qrow = b * 1024 + q0 + wave * 16 + lr;
    float* od = out + qrow * 768 + h * 64 + lg * 4;
    #pragma unroll
    for (int dt = 0; dt < 4; ++dt) {
        float4 v;
        v.x = o[dt][0] * inv; v.y = o[dt][1] * inv;
        v.z = o[dt][2] * inv; v.w = o[dt][3] * inv;
        *(float4*)(od + dt * 16) = v;
    }
}

extern "C" void kernel_launch(void* const* d_in, const int* in_sizes, int n_in,
                              void* d_out, int out_size, void* d_ws, size_t ws_size,
                              hipStream_t stream)
{
    const float* x  = (const float*)d_in[0];
    const float* y  = (const float*)d_in[1];
    const unsigned char* ym = (const unsigned char*)d_in[2];
    const float* Wq = (const float*)d_in[3];
    const float* bq = (const float*)d_in[4];
    const float* Wk = (const float*)d_in[5];
    const float* bk = (const float*)d_in[6];
    const float* Wv = (const float*)d_in[7];
    const float* bv = (const float*)d_in[8];

    _Float16* kws = (_Float16*)d_ws;             // [8192][768] fp16 K
    _Float16* vws = kws + 8192 * 768;            // [B][H*DV][L2] fp16 V^T
    _Float16* wt  = vws + 8192 * 768;            // [3][768][768] fp16 W^T (q,k,v)

    wtrans_kernel<<<dim3(24, 24, 3), 256, 0, stream>>>(Wq, Wk, Wv, wt);
    proj_kernel<<<dim3(64, 6, 2), 256, 0, stream>>>(y, wt, bk, bv, kws, vws);

    dim3 ag(16, 12, 8);
    attn_kernel<<<ag, 256, 0, stream>>>(x, wt, bq, kws, vws, ym, (float*)d_out);
}

// Round 9
// 129.815 us; speedup vs baseline: 2.0943x; 1.0345x over previous
//
#include <hip/hip_runtime.h>

typedef _Float16 half8 __attribute__((ext_vector_type(8)));
typedef _Float16 half4 __attribute__((ext_vector_type(4)));
typedef _Float16 half2 __attribute__((ext_vector_type(2)));
typedef __fp16  fp16x2 __attribute__((ext_vector_type(2)));
typedef float f32x4 __attribute__((ext_vector_type(4)));

static __device__ __forceinline__ half2 cvt_pk(float a, float b) {
    fp16x2 r = __builtin_amdgcn_cvt_pkrtz(a, b);
    return __builtin_bit_cast(half2, r);
}
static __device__ __forceinline__ float fdot2_acc(half2 a, half2 b, float c) {
    return __builtin_amdgcn_fdot2(__builtin_bit_cast(fp16x2, a),
                                  __builtin_bit_cast(fp16x2, b), c, false);
}

// B=8, L1=L2=1024, D_IN=768, H=12, DK=DV=64, M=B*L=8192

// ---------------------------------------------------------------------------
// One-time W transpose+convert: Wt[z][n][k] fp16 = W_z[k][n] fp32, z in {q,k,v}
// ---------------------------------------------------------------------------
__global__ __launch_bounds__(256)
void wtrans_kernel(const float* __restrict__ Wq, const float* __restrict__ Wk,
                   const float* __restrict__ Wv, _Float16* __restrict__ Wt)
{
    __shared__ float t[32][33];
    const float* W = (blockIdx.z == 0) ? Wq : (blockIdx.z == 1) ? Wk : Wv;
    _Float16* dst = Wt + blockIdx.z * 768 * 768;
    const int tx = threadIdx.x & 31, ty = threadIdx.x >> 5;
    const int k0 = blockIdx.y * 32, n0 = blockIdx.x * 32;
    #pragma unroll
    for (int i = 0; i < 4; ++i)
        t[ty + 8 * i][tx] = W[(k0 + ty + 8 * i) * 768 + n0 + tx];
    __syncthreads();
    #pragma unroll
    for (int i = 0; i < 4; ++i)
        dst[(n0 + ty + 8 * i) * 768 + k0 + tx] = (_Float16)t[tx][ty + 8 * i];
}

// ---------------------------------------------------------------------------
// Merged K/V projection GEMM: C[8192][768] = y @ W + bias -> fp16
// z=0: K, out[m*768+n].  z=1: V, out[(b*768+n)*1024 + (m&1023)] (Vt).
// ---------------------------------------------------------------------------
__global__ __launch_bounds__(256)
void proj_kernel(const float* __restrict__ A, const _Float16* __restrict__ Wt,
                 const float* __restrict__ bk, const float* __restrict__ bv,
                 _Float16* __restrict__ kout, _Float16* __restrict__ vout)
{
    __shared__ __align__(16) char smem[34816];
    _Float16* const Alds = (_Float16*)smem;            // [128][40] padded
    _Float16* const Wlds = (_Float16*)smem + 128 * 40; // [128][40] (W^T tile)
    _Float16* const Tlds = (_Float16*)smem;            // [128][136] epilogue

    const int tid  = threadIdx.x;
    const int lane = tid & 63;
    const int wave = tid >> 6;
    const int lr = lane & 15, lg = lane >> 4;
    const int wm = wave >> 1, wn = wave & 1;
    const int m0 = blockIdx.x * 128;
    const int n0 = blockIdx.y * 128;
    const int isv = blockIdx.z;

    const _Float16* __restrict__ W = Wt + (1 + isv) * 768 * 768;
    const float* __restrict__ bias = isv ? bv : bk;

    f32x4 acc[4][4] = {};

    const int ar   = tid >> 3;
    const int ac   = (tid & 7) * 4;
    const int wrow = tid >> 1;
    const int wcb  = (tid & 1) * 16;

    for (int kb = 0; kb < 24; ++kb) {
        #pragma unroll
        for (int i = 0; i < 4; ++i) {
            const int row = ar + 32 * i;
            const float4 v = *(const float4*)(A + (m0 + row) * 768 + kb * 32 + ac);
            half4 hh = { (_Float16)v.x, (_Float16)v.y, (_Float16)v.z, (_Float16)v.w };
            *(half4*)(Alds + row * 40 + ac) = hh;
        }
        {
            const _Float16* wtr = W + (n0 + wrow) * 768 + kb * 32 + wcb;
            *(uint4*)(Wlds + wrow * 40 + wcb)     = *(const uint4*)(wtr);
            *(uint4*)(Wlds + wrow * 40 + wcb + 8) = *(const uint4*)(wtr + 8);
        }
        __syncthreads();

        half8 af[4], bf[4];
        #pragma unroll
        for (int mt = 0; mt < 4; ++mt)
            af[mt] = *(const half8*)(Alds + (wm * 64 + mt * 16 + lr) * 40 + lg * 8);
        #pragma unroll
        for (int nt = 0; nt < 4; ++nt)
            bf[nt] = *(const half8*)(Wlds + (wn * 64 + nt * 16 + lr) * 40 + lg * 8);
        #pragma unroll
        for (int mt = 0; mt < 4; ++mt)
            #pragma unroll
            for (int nt = 0; nt < 4; ++nt)
                acc[mt][nt] = __builtin_amdgcn_mfma_f32_16x16x32_f16(af[mt], bf[nt], acc[mt][nt], 0, 0, 0);
        __syncthreads();
    }

    #pragma unroll
    for (int nt = 0; nt < 4; ++nt) {
        const int col = wn * 64 + nt * 16 + lr;
        const float bs = bias[n0 + col];
        #pragma unroll
        for (int mt = 0; mt < 4; ++mt) {
            #pragma unroll
            for (int r = 0; r < 4; ++r) {
                const int row = wm * 64 + mt * 16 + lg * 4 + r;
                const float val = acc[mt][nt][r] + bs;
                if (isv) Tlds[col * 136 + row] = (_Float16)val;
                else     Tlds[row * 136 + col] = (_Float16)val;
            }
        }
    }
    __syncthreads();

    const int crow = tid >> 1;
    const int cb   = (tid & 1) * 64;
    const _Float16* lsrc = Tlds + crow * 136 + cb;
    _Float16* gdst;
    if (isv) {
        const int bb  = m0 >> 10;
        const int l2b = m0 & 1023;
        gdst = vout + (bb * 768 + n0 + crow) * 1024 + l2b + cb;
    } else {
        gdst = kout + (m0 + crow) * 768 + n0 + cb;
    }
    #pragma unroll
    for (int it = 0; it < 8; ++it)
        *(uint4*)(gdst + it * 8) = *(const uint4*)(lsrc + it * 8);
}

// ---------------------------------------------------------------------------
// Fused attention: per block (q-tile=64, h, b).
// Phase 1: Q-tile projection, BK=64, async-staged; Q pre-scaled by 1/8.
// Phase 2: flash loop, KVBLK=64; exp2-domain softmax, fp16 mult. mask,
//          defer-max, fdot2 l-sum, P via per-wave LDS roundtrip.
// ---------------------------------------------------------------------------
__global__ __launch_bounds__(256)
void attn_kernel(const float* __restrict__ x, const _Float16* __restrict__ Wtq,
                 const float* __restrict__ bq,
                 const _Float16* __restrict__ K, const _Float16* __restrict__ Vt,
                 const unsigned char* __restrict__ mask,
                 float* __restrict__ out)
{
    __shared__ __align__(16) char smem[38912];
    _Float16* const Qlds = (_Float16*)smem;                  // [64][72]
    _Float16* const Klds = (_Float16*)(smem + 9216);         // ph1: x   [64][72]
    _Float16* const Vlds = (_Float16*)(smem + 18432);        // ph1: WqT [64][72]
    _Float16* const Plds = (_Float16*)(smem + 27648);        // [4 waves][16][72]
    _Float16* const Mh   = (_Float16*)(smem + 36864);        // [1024] fp16 0/1

    const int tid  = threadIdx.x;
    const int lane = tid & 63;
    const int wave = tid >> 6;
    const int lr = lane & 15, lg = lane >> 4;
    const int q0 = blockIdx.x * 64;
    const int h  = blockIdx.y;
    const int b  = blockIdx.z;

    const int pr = tid >> 2;            // 0..63 staging row
    const int pc = (tid & 3) * 16;      // staging col (16 elems)

    const float C2 = 1.44269504f;       // log2(e)

    // ---- phase 1: Q tile projection, BK=64, async-split ----
    {
        const float* xbase = x + (b * 1024 + q0 + pr) * 768 + pc;
        const _Float16* wbase = Wtq + (h * 64 + pr) * 768 + pc;
        float4 xa, xb, xc_, xd;
        uint4 wa, wb;
        xa = *(const float4*)(xbase);      xb = *(const float4*)(xbase + 4);
        xc_ = *(const float4*)(xbase + 8); xd = *(const float4*)(xbase + 12);
        wa = *(const uint4*)(wbase);       wb = *(const uint4*)(wbase + 8);

        f32x4 qacc[4] = {};
        for (int kb = 0; kb < 12; ++kb) {
            __syncthreads();
            union { half2 h[4]; half8 v; } u0, u1;
            u0.h[0] = cvt_pk(xa.x, xa.y);
            u0.h[1] = cvt_pk(xa.z, xa.w);
            u0.h[2] = cvt_pk(xb.x, xb.y);
            u0.h[3] = cvt_pk(xb.z, xb.w);
            u1.h[0] = cvt_pk(xc_.x, xc_.y);
            u1.h[1] = cvt_pk(xc_.z, xc_.w);
            u1.h[2] = cvt_pk(xd.x, xd.y);
            u1.h[3] = cvt_pk(xd.z, xd.w);
            *(half8*)(Klds + pr * 72 + pc)     = u0.v;
            *(half8*)(Klds + pr * 72 + pc + 8) = u1.v;
            *(uint4*)(Vlds + pr * 72 + pc)     = wa;
            *(uint4*)(Vlds + pr * 72 + pc + 8) = wb;
            __syncthreads();
            if (kb < 11) {
                const float* xn = xbase + (kb + 1) * 64;
                const _Float16* wn = wbase + (kb + 1) * 64;
                xa = *(const float4*)(xn);      xb = *(const float4*)(xn + 4);
                xc_ = *(const float4*)(xn + 8); xd = *(const float4*)(xn + 12);
                wa = *(const uint4*)(wn);       wb = *(const uint4*)(wn + 8);
            }
            half8 af[2];
            af[0] = *(const half8*)(Klds + (wave * 16 + lr) * 72 + lg * 8);
            af[1] = *(const half8*)(Klds + (wave * 16 + lr) * 72 + 32 + lg * 8);
            __builtin_amdgcn_s_setprio(1);
            #pragma unroll
            for (int nt = 0; nt < 4; ++nt) {
                #pragma unroll
                for (int s = 0; s < 2; ++s) {
                    const half8 bf = *(const half8*)(Vlds + (nt * 16 + lr) * 72 + s * 32 + lg * 8);
                    qacc[nt] = __builtin_amdgcn_mfma_f32_16x16x32_f16(af[s], bf, qacc[nt], 0, 0, 0);
                }
            }
            __builtin_amdgcn_s_setprio(0);
        }
        // Q = (xWq + bq) / 8  (scale folded so S = Q.K is pre-scaled)
        #pragma unroll
        for (int nt = 0; nt < 4; ++nt) {
            const int d = nt * 16 + lr;
            const float bs = bq[h * 64 + d];
            #pragma unroll
            for (int r = 0; r < 4; ++r)
                Qlds[(wave * 16 + lg * 4 + r) * 72 + d] = (_Float16)((qacc[nt][r] + bs) * 0.125f);
        }
        // fp16 multiplicative mask vector (1 = keep, 0 = masked)
        {
            const uchar4 mk = *(const uchar4*)(mask + b * 1024 + tid * 4);
            half4 mh = { mk.x ? (_Float16)0.f : (_Float16)1.f,
                         mk.y ? (_Float16)0.f : (_Float16)1.f,
                         mk.z ? (_Float16)0.f : (_Float16)1.f,
                         mk.w ? (_Float16)0.f : (_Float16)1.f };
            *(half4*)(Mh + tid * 4) = mh;
        }
        __syncthreads();
    }

    // Q fragment (B-operand of S^T)
    half8 qf[2];
    qf[0] = *(const half8*)(Qlds + (wave * 16 + lr) * 72 + lg * 8);
    qf[1] = *(const half8*)(Qlds + (wave * 16 + lr) * 72 + 32 + lg * 8);

    f32x4 o[4] = {};
    float m_run = -1e30f, l_run = 0.f;
    const half2 one2 = { (_Float16)1.f, (_Float16)1.f };

    const _Float16* const Kg = K + (b * 1024 + pr) * 768 + pc;
    const _Float16* const Vg = Vt + (b * 768 + h * 64 + pr) * 1024 + pc;
    _Float16* const Pw = Plds + wave * 1152;

    // prologue loads (kv tile 0)
    uint4 kr0, kr1, vr0, vr1;
    kr0 = *(const uint4*)(Kg + h * 64);
    kr1 = *(const uint4*)(Kg + h * 64 + 8);
    vr0 = *(const uint4*)(Vg);
    vr1 = *(const uint4*)(Vg + 8);

    for (int kt = 0; kt < 16; ++kt) {
        const int kv0 = kt * 64;
        __syncthreads();
        *(uint4*)(Klds + pr * 72 + pc)     = kr0;
        *(uint4*)(Klds + pr * 72 + pc + 8) = kr1;
        *(uint4*)(Vlds + pr * 72 + pc)     = vr0;
        *(uint4*)(Vlds + pr * 72 + pc + 8) = vr1;
        __syncthreads();
        if (kt < 15) {
            kr0 = *(const uint4*)(Kg + (kv0 + 64) * 768 + h * 64);
            kr1 = *(const uint4*)(Kg + (kv0 + 64) * 768 + h * 64 + 8);
            vr0 = *(const uint4*)(Vg + kv0 + 64);
            vr1 = *(const uint4*)(Vg + kv0 + 64 + 8);
        }

        // S^T: 4 kv-subtiles x 16 q (S pre-scaled via Q)
        f32x4 st[4] = {};
        __builtin_amdgcn_s_setprio(1);
        #pragma unroll
        for (int t4 = 0; t4 < 4; ++t4)
            #pragma unroll
            for (int s = 0; s < 2; ++s) {
                const half8 a = *(const half8*)(Klds + (t4 * 16 + lr) * 72 + s * 32 + lg * 8);
                st[t4] = __builtin_amdgcn_mfma_f32_16x16x32_f16(a, qf[s], st[t4], 0, 0, 0);
            }
        __builtin_amdgcn_s_setprio(0);

        // row max (masked rows included: any m >= true max is valid)
        float mx = fmaxf(
            fmaxf(fmaxf(fmaxf(st[0][0], st[0][1]), fmaxf(st[0][2], st[0][3])),
                  fmaxf(fmaxf(st[1][0], st[1][1]), fmaxf(st[1][2], st[1][3]))),
            fmaxf(fmaxf(fmaxf(st[2][0], st[2][1]), fmaxf(st[2][2], st[2][3])),
                  fmaxf(fmaxf(st[3][0], st[3][1]), fmaxf(st[3][2], st[3][3]))));
        mx = fmaxf(mx, __shfl_xor(mx, 16));
        mx = fmaxf(mx, __shfl_xor(mx, 32));

        // defer-max: rescale only when max grew by > 8 (P bounded by 2^11.5)
        if (!__all(mx <= m_run + 8.f)) {
            const float m_new = fmaxf(m_run, mx);
            const float corr = __builtin_amdgcn_exp2f((m_run - m_new) * C2);
            l_run *= corr;
            #pragma unroll
            for (int i = 0; i < 4; ++i) o[i] *= corr;
            m_run = m_new;
        }
        const float nb = -m_run * C2;

        // p = 2^(s*log2e - m*log2e); fp16 pack; mask-mul; l-sum via fdot2
        float ps = 0.f;
        #pragma unroll
        for (int t4 = 0; t4 < 4; ++t4) {
            half2 pa = cvt_pk(__builtin_amdgcn_exp2f(fmaf(st[t4][0], C2, nb)),
                              __builtin_amdgcn_exp2f(fmaf(st[t4][1], C2, nb)));
            half2 pb = cvt_pk(__builtin_amdgcn_exp2f(fmaf(st[t4][2], C2, nb)),
                              __builtin_amdgcn_exp2f(fmaf(st[t4][3], C2, nb)));
            const half4 mv = *(const half4*)(Mh + kv0 + t4 * 16 + lg * 4);
            const half2 m0 = { mv[0], mv[1] };
            const half2 m1 = { mv[2], mv[3] };
            pa *= m0;
            pb *= m1;
            ps = fdot2_acc(pa, one2, ps);
            ps = fdot2_acc(pb, one2, ps);
            union { half2 h[2]; half4 v; } pk;
            pk.h[0] = pa; pk.h[1] = pb;
            *(half4*)(Pw + lr * 72 + t4 * 16 + lg * 4) = pk.v;
        }
        ps += __shfl_xor(ps, 16);
        ps += __shfl_xor(ps, 32);
        l_run += ps;

        asm volatile("s_waitcnt lgkmcnt(0)" ::: "memory");
        __builtin_amdgcn_sched_barrier(0);

        half8 pf[2];
        pf[0] = *(const half8*)(Pw + lr * 72 + lg * 8);
        pf[1] = *(const half8*)(Pw + lr * 72 + 32 + lg * 8);

        // O^T += V^T @ P^T
        __builtin_amdgcn_s_setprio(1);
        #pragma unroll
        for (int dt = 0; dt < 4; ++dt)
            #pragma unroll
            for (int ks = 0; ks < 2; ++ks) {
                const half8 a = *(const half8*)(Vlds + (dt * 16 + lr) * 72 + ks * 32 + lg * 8);
                o[dt] = __builtin_amdgcn_mfma_f32_16x16x32_f16(a, pf[ks], o[dt], 0, 0, 0);
            }
        __builtin_amdgcn_s_setprio(0);
    }

    const float inv = 1.f / l_run;
    const int qrow = b * 1024 + q0 + wave * 16 + lr;
    float* od = out + qrow * 768 + h * 64 + lg * 4;
    #pragma unroll
    for (int dt = 0; dt < 4; ++dt) {
        float4 v;
        v.x = o[dt][0] * inv; v.y = o[dt][1] * inv;
        v.z = o[dt][2] * inv; v.w = o[dt][3] * inv;
        *(float4*)(od + dt * 16) = v;
    }
}

extern "C" void kernel_launch(void* const* d_in, const int* in_sizes, int n_in,
                              void* d_out, int out_size, void* d_ws, size_t ws_size,
                              hipStream_t stream)
{
    const float* x  = (const float*)d_in[0];
    const float* y  = (const float*)d_in[1];
    const unsigned char* ym = (const unsigned char*)d_in[2];
    const float* Wq = (const float*)d_in[3];
    const float* bq = (const float*)d_in[4];
    const float* Wk = (const float*)d_in[5];
    const float* bk = (const float*)d_in[6];
    const float* Wv = (const float*)d_in[7];
    const float* bv = (const float*)d_in[8];

    _Float16* kws = (_Float16*)d_ws;             // [8192][768] fp16 K
    _Float16* vws = kws + 8192 * 768;            // [B][H*DV][L2] fp16 V^T
    _Float16* wt  = vws + 8192 * 768;            // [3][768][768] fp16 W^T (q,k,v)

    wtrans_kernel<<<dim3(24, 24, 3), 256, 0, stream>>>(Wq, Wk, Wv, wt);
    proj_kernel<<<dim3(64, 6, 2), 256, 0, stream>>>(y, wt, bk, bv, kws, vws);

    dim3 ag(16, 12, 8);
    attn_kernel<<<ag, 256, 0, stream>>>(x, wt, bq, kws, vws, ym, (float*)d_out);
}